// Round 16
// baseline (318.984 us; speedup 1.0000x reference)
//
#include <hip/hip_runtime.h>
#include <hip/hip_cooperative_groups.h>

namespace cg = cooperative_groups;

typedef unsigned int uint;
typedef unsigned short ushort;
typedef unsigned long long u64;
typedef __attribute__((ext_vector_type(8))) short short8v;   // 8 bf16 in 4 VGPRs
typedef __attribute__((ext_vector_type(4))) float float4v;

#define NQ    32768
#define KALL  2048
#define E_DIM 256
#define HW    1024
#define TAU   2.5e-4f
#define S258  258     // fp32 LDS row stride for exact stage (2-way max on all ops)

// async global->LDS, 16B per lane; LDS dest = wave-uniform base + lane*16
#define GLOAD16(gsrc, ldst) \
    __builtin_amdgcn_global_load_lds( \
        (const __attribute__((address_space(1))) void*)(gsrc), \
        (__attribute__((address_space(3))) void*)(ldst), 16, 0, 0)

static __device__ __forceinline__ ushort f2bf(float f) {
    uint u = __float_as_uint(f);
    uint r = (u + 0x7fffu + ((u >> 16) & 1u)) >> 16;   // RNE, no NaN inputs
    return (ushort)r;
}

static __device__ __forceinline__ u64 u64min(u64 a, u64 b) { return a < b ? a : b; }

// ---- fused prep: blocks [0,512): codebook -> bf16 + csq (+ cnt zero);
// ----             blocks [512,2560): emb -> xb bf16 (+ xt fp32) ----
__global__ __launch_bounds__(256)
void prep_all(const float* __restrict__ emb, const float* __restrict__ cb,
              ushort* __restrict__ xb, ushort* __restrict__ cb1,
              float* __restrict__ csq, float* __restrict__ xt, int use_xt,
              int* __restrict__ cnt) {
    __shared__ float ldsf[64 * 65];
    const int t = threadIdx.x;

    if (blockIdx.x < 512) {               // ---- prep_cb ----
        if (blockIdx.x == 0 && t < 16) cnt[t] = 0;   // replaces memset launch
        int row  = blockIdx.x * 4 + (t >> 6);
        int lane = t & 63;
        float4 v = ((const float4*)cb)[row * 64 + lane];
        double s = (double)v.x * v.x + (double)v.y * v.y +
                   (double)v.z * v.z + (double)v.w * v.w;
        for (int m = 1; m < 64; m <<= 1) s += __shfl_xor(s, m);
        if (lane == 0) csq[row] = (float)s;    // fl32(exact ||c||^2)
        uint u0 = (uint)f2bf(v.x) | ((uint)f2bf(v.y) << 16);
        uint u1 = (uint)f2bf(v.z) | ((uint)f2bf(v.w) << 16);
        ((uint2*)cb1)[row * 64 + lane] = make_uint2(u0, u1);
        return;
    }

    // ---- prep_x ----
    int blk = blockIdx.x - 512;
    int img = blk >> 6;
    int tile = blk & 63;
    int e0  = (tile >> 4) * 64;
    int hw0 = (tile & 15) * 64;
    int rr4 = t >> 4;         // 0..15
    int c4  = t & 15;         // 0..15
    #pragma unroll
    for (int p = 0; p < 4; ++p) {          // float4 loads: 4 instrs vs 16 scalar
        int r = p * 16 + rr4;
        float4 v = *(const float4*)&emb[((img * 256 + e0 + r) << 10) + hw0 + c4 * 4];
        ldsf[(c4 * 4 + 0) * 65 + r] = v.x; // transpose into LDS (<=2-way: free)
        ldsf[(c4 * 4 + 1) * 65 + r] = v.y;
        ldsf[(c4 * 4 + 2) * 65 + r] = v.z;
        ldsf[(c4 * 4 + 3) * 65 + r] = v.w;
    }
    __syncthreads();
    int hr = t >> 5;          // 0..7
    int ep = t & 31;
    #pragma unroll 4
    for (int i = 0; i < 8; ++i) {
        int hwr = i * 8 + hr;
        float v0 = ldsf[hwr * 65 + ep * 2];
        float v1 = ldsf[hwr * 65 + ep * 2 + 1];
        uint u = (uint)f2bf(v0) | ((uint)f2bf(v1) << 16);
        size_t n = (size_t)(img * 1024 + hw0 + hwr);
        ((uint*)xb)[(n << 7) + (e0 >> 1) + ep] = u;
        if (use_xt)
            *(float2*)&xt[(n << 8) + e0 + ep * 2] = make_float2(v0, v1);
    }
}

// -- stage 1: bf16 MFMA GEMM, 2-phase dbuf + counted vmcnt, reg-top2 epilogue --
// Swapped-operand MFMA: D-rows = codes, D-cols = queries. (proven round-10/13 form)
__global__ __launch_bounds__(256, 2)
void vq_gemm2(const ushort* __restrict__ xb, const ushort* __restrict__ cb1,
              const float* __restrict__ csq,
              float* __restrict__ pm1, float* __restrict__ pm2,
              uint* __restrict__ pidxg) {
    __shared__ char stg[2][32768];       // [buf][ A 16KB | B 16KB ]
    __shared__ float e1[128][9];
    __shared__ float e2[128][9];
    __shared__ uint  ei[128][9];

    const int t = threadIdx.x;
    // XCD-chunked bijective swizzle (4096 blocks, 8 XCDs, 512 per XCD)
    const int bi = ((blockIdx.x & 7) << 9) | (blockIdx.x >> 3);
    const int mt = bi >> 4;              // 256 M-tiles
    const int nt = bi & 15;              // 16 N-tiles
    const int qbase = mt * 128;
    const int cbase = nt * 128;

    const int wid = t >> 6, lane = t & 63;
    const int wr = wid >> 1, wc = wid & 1;
    const int lr = lane & 15, lk = lane >> 4;

    float4v acc[4][4];                   // [fj: code blk][fi: query blk]
    #pragma unroll
    for (int i = 0; i < 4; ++i)
        #pragma unroll
        for (int j = 0; j < 4; ++j)
            acc[i][j] = (float4v){0.f, 0.f, 0.f, 0.f};

    const int srow = lane >> 3;          // 0..7 within 8-row chunk
    const int sslot = lane & 7;          // 16B slot within row

    // prologue: stage K-step 0 into buf 0
    #pragma unroll
    for (int i = 0; i < 4; ++i) {
        int ch  = wid * 4 + i;
        int row = ch * 8 + srow;
        int sl  = sslot ^ (row & 7);
        GLOAD16(xb  + (size_t)(qbase + row) * 256 + sl * 8, &stg[0][0]     + ch * 1024);
        GLOAD16(cb1 + (size_t)(cbase + row) * 256 + sl * 8, &stg[0][16384] + ch * 1024);
    }

    #pragma unroll
    for (int kt = 0; kt < 4; ++kt) {
        const int cur = kt & 1;
        if (kt < 3) {                    // stage next K-step into other buf
            const int kofs = (kt + 1) * 64;
            #pragma unroll
            for (int i = 0; i < 4; ++i) {
                int ch  = wid * 4 + i;
                int row = ch * 8 + srow;
                int sl  = sslot ^ (row & 7);
                GLOAD16(xb  + (size_t)(qbase + row) * 256 + kofs + sl * 8,
                        &stg[cur ^ 1][0] + ch * 1024);
                GLOAD16(cb1 + (size_t)(cbase + row) * 256 + kofs + sl * 8,
                        &stg[cur ^ 1][16384] + ch * 1024);
            }
            asm volatile("s_waitcnt vmcnt(8)" ::: "memory");   // current buf landed
        } else {
            asm volatile("s_waitcnt vmcnt(0)" ::: "memory");
        }
        __builtin_amdgcn_sched_barrier(0);
        __builtin_amdgcn_s_barrier();    // all waves' loads landed
        __builtin_amdgcn_sched_barrier(0);

        const char* Asm = &stg[cur][0];
        const char* Bsm = &stg[cur][16384];
        #pragma unroll
        for (int ks = 0; ks < 2; ++ks) {
            short8v af[4], bfv[4];
            #pragma unroll
            for (int f = 0; f < 4; ++f) {
                int ra = wr * 64 + f * 16 + lr;
                int sa = ((ks << 2) | lk) ^ (ra & 7);
                af[f] = *(const short8v*)(Asm + ra * 128 + sa * 16);
                int rb = wc * 64 + f * 16 + lr;
                int sb = ((ks << 2) | lk) ^ (rb & 7);
                bfv[f] = *(const short8v*)(Bsm + rb * 128 + sb * 16);
            }
            #pragma unroll
            for (int fj = 0; fj < 4; ++fj)
                #pragma unroll
                for (int fi = 0; fi < 4; ++fi)
                    acc[fj][fi] = __builtin_amdgcn_mfma_f32_16x16x32_bf16(
                        bfv[fj], af[fi], acc[fj][fi], 0, 0, 0);
        }
        __builtin_amdgcn_s_barrier();    // reads retired; buffer reusable
    }

    // per-lane csq for its 16 codes (cloc = wc*64 + fj*16 + lk*4 + r); L2-hot
    float csqv[16];
    #pragma unroll
    for (int fj = 0; fj < 4; ++fj)
        #pragma unroll
        for (int r = 0; r < 4; ++r)
            csqv[fj * 4 + r] = csq[cbase + wc * 64 + fj * 16 + lk * 4 + r];

    // phase 1: per-lane top2 over 16 codes for query (fi, lr); write [q][wc*4+lk]
    #pragma unroll
    for (int fi = 0; fi < 4; ++fi) {
        float m1 = 3e38f, m2 = 3e38f; uint i1 = 0;
        #pragma unroll
        for (int fj = 0; fj < 4; ++fj)
            #pragma unroll
            for (int r = 0; r < 4; ++r) {
                float s = fmaf(-2.0f, acc[fj][fi][r], csqv[fj * 4 + r]);
                uint gidx = (uint)(cbase + wc * 64 + fj * 16 + lk * 4 + r);
                if (s < m1) { m2 = m1; m1 = s; i1 = gidx; }
                else        { m2 = fminf(m2, s); }
            }
        int q = wr * 64 + fi * 16 + lr;
        int col = wc * 4 + lk;
        e1[q][col] = m1; e2[q][col] = m2; ei[q][col] = i1;
    }
    __syncthreads();

    // phase 2: q = t>>1; halves merge 4 entries each, then shfl_xor(1)
    {
        int q = t >> 1, h = t & 1;
        float m1 = 3e38f, m2 = 3e38f; uint i1 = 0;
        #pragma unroll
        for (int j = 0; j < 4; ++j) {
            int col = h * 4 + j;
            float a1 = e1[q][col], a2 = e2[q][col];
            uint  ai = ei[q][col];
            if (a1 < m1) { m2 = fminf(m1, a2); m1 = a1; i1 = ai; }
            else         { m2 = fminf(m2, a1); }
        }
        float o1 = __shfl_xor(m1, 1);
        float o2 = __shfl_xor(m2, 1);
        uint  oi = __shfl_xor(i1, 1);
        if (o1 < m1) { m2 = fminf(m1, o2); m1 = o1; i1 = oi; }
        else         { m2 = fminf(m2, o1); }
        if (h == 0) {
            size_t og = (size_t)nt * NQ + qbase + q;   // [nt][NQ]: coalesced
            pm1[og] = m1;
            pm2[og] = m2;
            pidxg[og] = i1;
        }
    }
}

// ---- fused tail (cooperative): merge -> grid.sync -> exact -> grid.sync -> gather ----
// Grid 512 x 256: co-residency 2 blocks/CU (17KB LDS, VGPR well under budget).
__global__ __launch_bounds__(256)
void vq_tail(const float* __restrict__ emb, const float* __restrict__ xt,
             int use_xt, const float* __restrict__ cb,
             const float* __restrict__ csq, const float* __restrict__ pm1,
             const float* __restrict__ pm2, const uint* __restrict__ pidxg,
             int* __restrict__ idxout, int* __restrict__ bucket,
             int* __restrict__ cnt, u64* __restrict__ best64,
             float* __restrict__ out) {
    __shared__ float xs[16 * S258];      // 16.5 KB: 16 query rows, fp32
    __shared__ u64   pkq[16];
    __shared__ float xsl[16];
    __shared__ int   qids[16];

    cg::grid_group grid = cg::this_grid();
    const int t   = threadIdx.x;
    const int blk = blockIdx.x;

    // ================= phase 1: merge (blocks 0..127) =================
    if (blk < 128) {
        int q = blk * 256 + t;
        best64[q] = ~0ULL;
        float g1 = 3e38f, g2 = 3e38f; uint gi = 0;
        float m1v[16];
        #pragma unroll
        for (int tl = 0; tl < 16; ++tl) {
            float a1 = pm1[(size_t)tl * NQ + q];
            float a2 = pm2[(size_t)tl * NQ + q];
            uint  ai = pidxg[(size_t)tl * NQ + q];
            m1v[tl] = a1;
            if (a1 < g1) { g2 = fminf(g1, a2); g1 = a1; gi = ai; }
            else         { g2 = fminf(g2, a1); }
        }
        idxout[q] = (int)gi;
        if (g2 - g1 < TAU) {
            float lim = g1 + TAU;
            #pragma unroll
            for (int tl = 0; tl < 16; ++tl) {
                if (m1v[tl] < lim) {       // candidate tile: could hold the true winner
                    int p = atomicAdd(&cnt[tl], 1);
                    bucket[tl * NQ + p] = q;
                }
            }
        }
    }
    __threadfence();
    grid.sync();

    // ================= phase 2: exact fp64 (all 512 blocks) =================
    {
        const int tile  = blk >> 5;           // 0..15
        const int qslot = (blk >> 1) & 15;    // 0..15
        const int chalf = blk & 1;            // 0..1
        const int cn = cnt[tile];

        const int r16 = t >> 4, es = t & 15;  // staging: 16 rows x 16 lanes
        const int ds = t & 3;                 // dim quarter
        const int p  = t >> 2;                // 0..63
        const int cg_ = p & 7, qg = (p >> 3) & 3, ch = p >> 5;

        for (int base = qslot * 16; base < cn; base += 16 * 16) {
            const int nq = min(16, cn - base);
            __syncthreads();                          // prior iteration fully done
            if (t < 16) {
                pkq[t]  = ~0ULL;
                qids[t] = (t < nq) ? bucket[tile * NQ + base + t] : 0;
            }
            __syncthreads();

            // ---- stage 16 query rows (fp32) + exact ||x||^2 ----
            {
                double xp = 0.0;
                float* xrow = &xs[r16 * S258];
                if (r16 < nq) {
                    const int q = qids[r16];
                    if (use_xt) {                     // coalesced: 16 lanes x 4 float4
                        const float4* __restrict__ src =
                            (const float4*)(xt + ((size_t)q << 8));
                        #pragma unroll
                        for (int j = 0; j < 4; ++j) { // dims j*64 + es*4 .. +3
                            float4 v = src[j * 16 + es];
                            *(float4*)&xrow[j * 64 + es * 4] = v;
                            xp = fma((double)v.x, (double)v.x, xp);
                            xp = fma((double)v.y, (double)v.y, xp);
                            xp = fma((double)v.z, (double)v.z, xp);
                            xp = fma((double)v.w, (double)v.w, xp);
                        }
                    } else {                          // fallback: scattered 4B loads
                        const int b = q >> 10, hw = q & 1023;
                        const float* __restrict__ ep = emb + ((size_t)b << 18) + hw;
                        #pragma unroll
                        for (int j = 0; j < 4; ++j) {
                            float vv[4];
                            #pragma unroll
                            for (int jj = 0; jj < 4; ++jj) {
                                int e = j * 64 + es * 4 + jj;
                                vv[jj] = ep[(size_t)e << 10];
                                xp = fma((double)vv[jj], (double)vv[jj], xp);
                            }
                            *(float4*)&xrow[j * 64 + es * 4] =
                                make_float4(vv[0], vv[1], vv[2], vv[3]);
                        }
                    }
                } else {
                    #pragma unroll
                    for (int j = 0; j < 4; ++j)
                        *(float4*)&xrow[j * 64 + es * 4] =
                            make_float4(0.f, 0.f, 0.f, 0.f);
                }
                xp += __shfl_xor(xp, 1);
                xp += __shfl_xor(xp, 2);
                xp += __shfl_xor(xp, 4);
                xp += __shfl_xor(xp, 8);
                if (es == 0) xsl[r16] = (float)xp;    // fl32(exact ||x||^2)
            }
            __syncthreads();                          // xs + xsl ready

            // ---- 4q x 4c micro-tile; c rows straight from L1/L2 ----
            const int crow0 = tile * 128 + chalf * 64 + ch * 32 + cg_ * 4;
            double a[4][4];
            #pragma unroll
            for (int qi = 0; qi < 4; ++qi)
                #pragma unroll
                for (int ci = 0; ci < 4; ++ci) a[qi][ci] = 0.0;

            const float* __restrict__ xq = &xs[(qg * 4) * S258 + ds * 4];
            const float* __restrict__ cq = cb + (size_t)crow0 * 256 + ds * 4;
            #pragma unroll 4
            for (int dd = 0; dd < 16; ++dd) {
                const int off = dd * 16;              // dims dd*16 + ds*4 + j
                float4 xv[4], cv[4];
                #pragma unroll
                for (int qi = 0; qi < 4; ++qi)
                    xv[qi] = *(const float4*)&xq[qi * S258 + off];
                #pragma unroll
                for (int ci = 0; ci < 4; ++ci)
                    cv[ci] = *(const float4*)&cq[ci * 256 + off];   // global, L1-hot
                #pragma unroll
                for (int qi = 0; qi < 4; ++qi)
                    #pragma unroll
                    for (int ci = 0; ci < 4; ++ci) {
                        a[qi][ci] = fma((double)xv[qi].x, (double)cv[ci].x, a[qi][ci]);
                        a[qi][ci] = fma((double)xv[qi].y, (double)cv[ci].y, a[qi][ci]);
                        a[qi][ci] = fma((double)xv[qi].z, (double)cv[ci].z, a[qi][ci]);
                        a[qi][ci] = fma((double)xv[qi].w, (double)cv[ci].w, a[qi][ci]);
                    }
            }

            // reduce dim quarters (lanes xor 1,2) -> ds==0 holds full fp64 dots
            #pragma unroll
            for (int qi = 0; qi < 4; ++qi)
                #pragma unroll
                for (int ci = 0; ci < 4; ++ci) {
                    double v = a[qi][ci];
                    v += __shfl_xor(v, 1);
                    v += __shfl_xor(v, 2);
                    a[qi][ci] = v;
                }
            if (ds == 0) {
                float4 csqv = *(const float4*)&csq[crow0];
                #pragma unroll
                for (int qi = 0; qi < 4; ++qi) {
                    const float xsv = xsl[qg * 4 + qi];
                    u64 pk = ~0ULL;
                    #pragma unroll
                    for (int ci = 0; ci < 4; ++ci) {
                        float g = (float)a[qi][ci];            // fl32(exact dot)
                        float G = g + g;
                        float csv = (ci == 0) ? csqv.x : (ci == 1) ? csqv.y
                                  : (ci == 2) ? csqv.z : csqv.w;
                        float d = (xsv - G) + csv;             // fp32 rounding replay
                        uint gidx = (uint)(crow0 + ci);
                        pk = u64min(pk, ((u64)__float_as_uint(d) << 32) | gidx);
                    }
                    atomicMin(&pkq[qg * 4 + qi], pk);
                }
            }
            __syncthreads();                           // pkq final
            if (t < nq) atomicMin(&best64[qids[t]], pkq[t]);  // (d,idx): numpy tiebreak
        }
    }
    __threadfence();
    grid.sync();

    // ================= phase 3: gather (all 512 blocks, 64 q each) =================
    {
        int n  = blk * 64 + (t >> 2);
        int eg = t & 3;
        u64 pk = best64[n];
        int bi = (pk != ~0ULL) ? (int)(pk & 0xffffffffu) : idxout[n];
        int b = n >> 10, hw = n & 1023;
        const float4* __restrict__ row = (const float4*)(cb + (size_t)bi * 256);
        float* __restrict__ outB = out + (size_t)b * 256 * HW + hw;
        #pragma unroll 4
        for (int j = 0; j < 16; ++j) {
            int e4 = eg * 16 + j;
            float4 c = row[e4];
            outB[(size_t)(e4 * 4 + 0) * HW] = c.x;
            outB[(size_t)(e4 * 4 + 1) * HW] = c.y;
            outB[(size_t)(e4 * 4 + 2) * HW] = c.z;
            outB[(size_t)(e4 * 4 + 3) * HW] = c.w;
        }
    }
}

extern "C" void kernel_launch(void* const* d_in, const int* in_sizes, int n_in,
                              void* d_out, int out_size, void* d_ws, size_t ws_size,
                              hipStream_t stream) {
    const float* emb = (const float*)d_in[0];   // [32, 256, 32, 32] fp32
    const float* cb  = (const float*)d_in[1];   // [2048, 256] fp32
    float* out = (float*)d_out;

    char* ws = (char*)d_ws;
    ushort* xb     = (ushort*)ws;                        // 16 MB
    ushort* cb1    = (ushort*)(ws + 16777216);           // 1 MB
    float*  csq    = (float*) (ws + 17825792);           // 8 KB
    float*  pm1    = (float*) (ws + 17833984);           // 2 MB  [16][NQ]
    float*  pm2    = (float*) (ws + 19931136);           // 2 MB  [16][NQ]
    uint*   pidxg  = (uint*)  (ws + 22028288);           // 2 MB  [16][NQ]
    int*    idxout = (int*)   (ws + 24125440);           // 128 KB
    int*    bucket = (int*)   (ws + 24256512);           // 2 MB (16 x 32768)
    int*    cnt    = (int*)   (ws + 26353664);           // 256 B
    u64*    best64 = (u64*)   (ws + 26353920);           // 256 KB
    float*  xt     = (float*) (ws + 26616064);           // 32 MB (optional)
    int use_xt = (ws_size >= (size_t)26616064 + 33554432) ? 1 : 0;

    prep_all <<<2560, 256, 0, stream>>>(emb, cb, xb, cb1, csq, xt, use_xt, cnt);
    vq_gemm2 <<<4096, 256, 0, stream>>>(xb, cb1, csq, pm1, pm2, pidxg);

    void* args[] = { (void*)&emb, (void*)&xt, (void*)&use_xt, (void*)&cb,
                     (void*)&csq, (void*)&pm1, (void*)&pm2, (void*)&pidxg,
                     (void*)&idxout, (void*)&bucket, (void*)&cnt,
                     (void*)&best64, (void*)&out };
    hipLaunchCooperativeKernel((void*)vq_tail, dim3(512), dim3(256), args, 0, stream);
}

// Round 17
// 153.545 us; speedup vs baseline: 2.0775x; 2.0775x over previous
//
#include <hip/hip_runtime.h>

typedef unsigned int uint;
typedef unsigned short ushort;
typedef unsigned long long u64;
typedef __attribute__((ext_vector_type(8))) short short8v;   // 8 bf16 in 4 VGPRs
typedef __attribute__((ext_vector_type(4))) float float4v;

#define NQ    32768
#define KALL  2048
#define E_DIM 256
#define HW    1024
#define TAU   2.5e-4f
#define S258  258     // fp32 LDS row stride for exact stage (2-way max on all ops)

// async global->LDS, 16B per lane; LDS dest = wave-uniform base + lane*16
#define GLOAD16(gsrc, ldst) \
    __builtin_amdgcn_global_load_lds( \
        (const __attribute__((address_space(1))) void*)(gsrc), \
        (__attribute__((address_space(3))) void*)(ldst), 16, 0, 0)

static __device__ __forceinline__ ushort f2bf(float f) {
    uint u = __float_as_uint(f);
    uint r = (u + 0x7fffu + ((u >> 16) & 1u)) >> 16;   // RNE, no NaN inputs
    return (ushort)r;
}

static __device__ __forceinline__ u64 u64min(u64 a, u64 b) { return a < b ? a : b; }

// ---- fused prep: blocks [0,512): codebook -> bf16 + csq (+ cnt zero);
// ----             blocks [512,2560): emb -> xb bf16 (+ xt fp32) ----
__global__ __launch_bounds__(256)
void prep_all(const float* __restrict__ emb, const float* __restrict__ cb,
              ushort* __restrict__ xb, ushort* __restrict__ cb1,
              float* __restrict__ csq, float* __restrict__ xt, int use_xt,
              int* __restrict__ cnt) {
    __shared__ float ldsf[64 * 65];
    const int t = threadIdx.x;

    if (blockIdx.x < 512) {               // ---- prep_cb ----
        if (blockIdx.x == 0 && t < 16) cnt[t] = 0;   // replaces memset launch
        int row  = blockIdx.x * 4 + (t >> 6);
        int lane = t & 63;
        float4 v = ((const float4*)cb)[row * 64 + lane];
        double s = (double)v.x * v.x + (double)v.y * v.y +
                   (double)v.z * v.z + (double)v.w * v.w;
        for (int m = 1; m < 64; m <<= 1) s += __shfl_xor(s, m);
        if (lane == 0) csq[row] = (float)s;    // fl32(exact ||c||^2)
        uint u0 = (uint)f2bf(v.x) | ((uint)f2bf(v.y) << 16);
        uint u1 = (uint)f2bf(v.z) | ((uint)f2bf(v.w) << 16);
        ((uint2*)cb1)[row * 64 + lane] = make_uint2(u0, u1);
        return;
    }

    // ---- prep_x ----
    int blk = blockIdx.x - 512;
    int img = blk >> 6;
    int tile = blk & 63;
    int e0  = (tile >> 4) * 64;
    int hw0 = (tile & 15) * 64;
    int rr4 = t >> 4;         // 0..15
    int c4  = t & 15;         // 0..15
    #pragma unroll
    for (int p = 0; p < 4; ++p) {          // float4 loads: 4 instrs vs 16 scalar
        int r = p * 16 + rr4;
        float4 v = *(const float4*)&emb[((img * 256 + e0 + r) << 10) + hw0 + c4 * 4];
        ldsf[(c4 * 4 + 0) * 65 + r] = v.x; // transpose into LDS (<=2-way: free)
        ldsf[(c4 * 4 + 1) * 65 + r] = v.y;
        ldsf[(c4 * 4 + 2) * 65 + r] = v.z;
        ldsf[(c4 * 4 + 3) * 65 + r] = v.w;
    }
    __syncthreads();
    int hr = t >> 5;          // 0..7
    int ep = t & 31;
    #pragma unroll 4
    for (int i = 0; i < 8; ++i) {
        int hwr = i * 8 + hr;
        float v0 = ldsf[hwr * 65 + ep * 2];
        float v1 = ldsf[hwr * 65 + ep * 2 + 1];
        uint u = (uint)f2bf(v0) | ((uint)f2bf(v1) << 16);
        size_t n = (size_t)(img * 1024 + hw0 + hwr);
        ((uint*)xb)[(n << 7) + (e0 >> 1) + ep] = u;
        if (use_xt)
            *(float2*)&xt[(n << 8) + e0 + ep * 2] = make_float2(v0, v1);
    }
}

// -- stage 1: bf16 MFMA GEMM, 2-phase dbuf + counted vmcnt, reg-top2 epilogue --
// Swapped-operand MFMA: D-rows = codes, D-cols = queries. (proven round-10/13 form)
__global__ __launch_bounds__(256, 2)
void vq_gemm2(const ushort* __restrict__ xb, const ushort* __restrict__ cb1,
              const float* __restrict__ csq,
              float* __restrict__ pm1, float* __restrict__ pm2,
              uint* __restrict__ pidxg) {
    __shared__ char stg[2][32768];       // [buf][ A 16KB | B 16KB ]
    __shared__ float e1[128][9];
    __shared__ float e2[128][9];
    __shared__ uint  ei[128][9];

    const int t = threadIdx.x;
    // XCD-chunked bijective swizzle (4096 blocks, 8 XCDs, 512 per XCD)
    const int bi = ((blockIdx.x & 7) << 9) | (blockIdx.x >> 3);
    const int mt = bi >> 4;              // 256 M-tiles
    const int nt = bi & 15;              // 16 N-tiles
    const int qbase = mt * 128;
    const int cbase = nt * 128;

    const int wid = t >> 6, lane = t & 63;
    const int wr = wid >> 1, wc = wid & 1;
    const int lr = lane & 15, lk = lane >> 4;

    float4v acc[4][4];                   // [fj: code blk][fi: query blk]
    #pragma unroll
    for (int i = 0; i < 4; ++i)
        #pragma unroll
        for (int j = 0; j < 4; ++j)
            acc[i][j] = (float4v){0.f, 0.f, 0.f, 0.f};

    const int srow = lane >> 3;          // 0..7 within 8-row chunk
    const int sslot = lane & 7;          // 16B slot within row

    // prologue: stage K-step 0 into buf 0
    #pragma unroll
    for (int i = 0; i < 4; ++i) {
        int ch  = wid * 4 + i;
        int row = ch * 8 + srow;
        int sl  = sslot ^ (row & 7);
        GLOAD16(xb  + (size_t)(qbase + row) * 256 + sl * 8, &stg[0][0]     + ch * 1024);
        GLOAD16(cb1 + (size_t)(cbase + row) * 256 + sl * 8, &stg[0][16384] + ch * 1024);
    }

    #pragma unroll
    for (int kt = 0; kt < 4; ++kt) {
        const int cur = kt & 1;
        if (kt < 3) {                    // stage next K-step into other buf
            const int kofs = (kt + 1) * 64;
            #pragma unroll
            for (int i = 0; i < 4; ++i) {
                int ch  = wid * 4 + i;
                int row = ch * 8 + srow;
                int sl  = sslot ^ (row & 7);
                GLOAD16(xb  + (size_t)(qbase + row) * 256 + kofs + sl * 8,
                        &stg[cur ^ 1][0] + ch * 1024);
                GLOAD16(cb1 + (size_t)(cbase + row) * 256 + kofs + sl * 8,
                        &stg[cur ^ 1][16384] + ch * 1024);
            }
            asm volatile("s_waitcnt vmcnt(8)" ::: "memory");   // current buf landed
        } else {
            asm volatile("s_waitcnt vmcnt(0)" ::: "memory");
        }
        __builtin_amdgcn_sched_barrier(0);
        __builtin_amdgcn_s_barrier();    // all waves' loads landed
        __builtin_amdgcn_sched_barrier(0);

        const char* Asm = &stg[cur][0];
        const char* Bsm = &stg[cur][16384];
        #pragma unroll
        for (int ks = 0; ks < 2; ++ks) {
            short8v af[4], bfv[4];
            #pragma unroll
            for (int f = 0; f < 4; ++f) {
                int ra = wr * 64 + f * 16 + lr;
                int sa = ((ks << 2) | lk) ^ (ra & 7);
                af[f] = *(const short8v*)(Asm + ra * 128 + sa * 16);
                int rb = wc * 64 + f * 16 + lr;
                int sb = ((ks << 2) | lk) ^ (rb & 7);
                bfv[f] = *(const short8v*)(Bsm + rb * 128 + sb * 16);
            }
            #pragma unroll
            for (int fj = 0; fj < 4; ++fj)
                #pragma unroll
                for (int fi = 0; fi < 4; ++fi)
                    acc[fj][fi] = __builtin_amdgcn_mfma_f32_16x16x32_bf16(
                        bfv[fj], af[fi], acc[fj][fi], 0, 0, 0);
        }
        __builtin_amdgcn_s_barrier();    // reads retired; buffer reusable
    }

    // per-lane csq for its 16 codes (cloc = wc*64 + fj*16 + lk*4 + r); L2-hot
    float csqv[16];
    #pragma unroll
    for (int fj = 0; fj < 4; ++fj)
        #pragma unroll
        for (int r = 0; r < 4; ++r)
            csqv[fj * 4 + r] = csq[cbase + wc * 64 + fj * 16 + lk * 4 + r];

    // phase 1: per-lane top2 over 16 codes for query (fi, lr); write [q][wc*4+lk]
    #pragma unroll
    for (int fi = 0; fi < 4; ++fi) {
        float m1 = 3e38f, m2 = 3e38f; uint i1 = 0;
        #pragma unroll
        for (int fj = 0; fj < 4; ++fj)
            #pragma unroll
            for (int r = 0; r < 4; ++r) {
                float s = fmaf(-2.0f, acc[fj][fi][r], csqv[fj * 4 + r]);
                uint gidx = (uint)(cbase + wc * 64 + fj * 16 + lk * 4 + r);
                if (s < m1) { m2 = m1; m1 = s; i1 = gidx; }
                else        { m2 = fminf(m2, s); }
            }
        int q = wr * 64 + fi * 16 + lr;
        int col = wc * 4 + lk;
        e1[q][col] = m1; e2[q][col] = m2; ei[q][col] = i1;
    }
    __syncthreads();

    // phase 2: q = t>>1; halves merge 4 entries each, then shfl_xor(1)
    {
        int q = t >> 1, h = t & 1;
        float m1 = 3e38f, m2 = 3e38f; uint i1 = 0;
        #pragma unroll
        for (int j = 0; j < 4; ++j) {
            int col = h * 4 + j;
            float a1 = e1[q][col], a2 = e2[q][col];
            uint  ai = ei[q][col];
            if (a1 < m1) { m2 = fminf(m1, a2); m1 = a1; i1 = ai; }
            else         { m2 = fminf(m2, a1); }
        }
        float o1 = __shfl_xor(m1, 1);
        float o2 = __shfl_xor(m2, 1);
        uint  oi = __shfl_xor(i1, 1);
        if (o1 < m1) { m2 = fminf(m1, o2); m1 = o1; i1 = oi; }
        else         { m2 = fminf(m2, o1); }
        if (h == 0) {
            size_t og = (size_t)nt * NQ + qbase + q;   // [nt][NQ]: coalesced
            pm1[og] = m1;
            pm2[og] = m2;
            pidxg[og] = i1;
        }
    }
}

// ---- merge tiles, flag near-ties into per-tile buckets; init best64 ----
__global__ __launch_bounds__(256)
void vq_merge(const float* __restrict__ pm1, const float* __restrict__ pm2,
              const uint* __restrict__ pidxg, int* __restrict__ idxout,
              int* __restrict__ bucket, int* __restrict__ cnt,
              u64* __restrict__ best64) {
    int q = blockIdx.x * 256 + threadIdx.x;
    best64[q] = ~0ULL;                    // replaces memset launch (runs pre-exact5)
    float g1 = 3e38f, g2 = 3e38f; uint gi = 0;
    float m1v[16];
    #pragma unroll
    for (int tl = 0; tl < 16; ++tl) {
        float a1 = pm1[(size_t)tl * NQ + q];
        float a2 = pm2[(size_t)tl * NQ + q];
        uint  ai = pidxg[(size_t)tl * NQ + q];
        m1v[tl] = a1;
        if (a1 < g1) { g2 = fminf(g1, a2); g1 = a1; gi = ai; }
        else         { g2 = fminf(g2, a1); }
    }
    idxout[q] = (int)gi;
    if (g2 - g1 < TAU) {
        float lim = g1 + TAU;
        #pragma unroll
        for (int tl = 0; tl < 16; ++tl) {
            if (m1v[tl] < lim) {           // candidate tile: could hold the true winner
                int p = atomicAdd(&cnt[tl], 1);
                bucket[tl * NQ + p] = q;
            }
        }
    }
}

// ------- stage 2: exact fp64 micro-GEMM; x in LDS, codebook direct from L2 -------
__global__ __launch_bounds__(256)
void vq_exact5(const float* __restrict__ emb, const float* __restrict__ xt,
               int use_xt, const float* __restrict__ cb,
               const float* __restrict__ csq, const int* __restrict__ bucket,
               const int* __restrict__ cnt, u64* __restrict__ best64) {
    __shared__ float xs[16 * S258];      // 16.5 KB: 16 query rows, fp32
    __shared__ u64   pkq[16];
    __shared__ float xsl[16];
    __shared__ int   qids[16];

    const int tile  = blockIdx.x >> 6;        // 0..15
    const int qslot = (blockIdx.x >> 1) & 31; // 0..31
    const int chalf = blockIdx.x & 1;         // 0..1
    const int t  = threadIdx.x;
    const int cn = cnt[tile];

    const int r16 = t >> 4, es = t & 15;  // staging: 16 rows x 16 lanes
    const int ds = t & 3;                 // dim quarter
    const int p  = t >> 2;                // 0..63
    const int cg = p & 7, qg = (p >> 3) & 3, ch = p >> 5;

    for (int base = qslot * 16; base < cn; base += 32 * 16) {
        const int nq = min(16, cn - base);
        __syncthreads();                          // prior iteration fully done
        if (t < 16) {
            pkq[t]  = ~0ULL;
            qids[t] = (t < nq) ? bucket[tile * NQ + base + t] : 0;
        }
        __syncthreads();

        // ---- stage 16 query rows (fp32) + exact ||x||^2 ----
        {
            double xp = 0.0;
            float* xrow = &xs[r16 * S258];
            if (r16 < nq) {
                const int q = qids[r16];
                if (use_xt) {                     // coalesced: 16 lanes x 4 float4
                    const float4* __restrict__ src = (const float4*)(xt + ((size_t)q << 8));
                    #pragma unroll
                    for (int j = 0; j < 4; ++j) { // dims j*64 + es*4 .. +3
                        float4 v = src[j * 16 + es];
                        *(float4*)&xrow[j * 64 + es * 4] = v;
                        xp = fma((double)v.x, (double)v.x, xp);
                        xp = fma((double)v.y, (double)v.y, xp);
                        xp = fma((double)v.z, (double)v.z, xp);
                        xp = fma((double)v.w, (double)v.w, xp);
                    }
                } else {                          // fallback: scattered 4B loads
                    const int b = q >> 10, hw = q & 1023;
                    const float* __restrict__ ep = emb + ((size_t)b << 18) + hw;
                    #pragma unroll
                    for (int j = 0; j < 4; ++j) {
                        float vv[4];
                        #pragma unroll
                        for (int jj = 0; jj < 4; ++jj) {
                            int e = j * 64 + es * 4 + jj;
                            vv[jj] = ep[(size_t)e << 10];
                            xp = fma((double)vv[jj], (double)vv[jj], xp);
                        }
                        *(float4*)&xrow[j * 64 + es * 4] =
                            make_float4(vv[0], vv[1], vv[2], vv[3]);
                    }
                }
            } else {
                #pragma unroll
                for (int j = 0; j < 4; ++j)
                    *(float4*)&xrow[j * 64 + es * 4] = make_float4(0.f, 0.f, 0.f, 0.f);
            }
            xp += __shfl_xor(xp, 1);
            xp += __shfl_xor(xp, 2);
            xp += __shfl_xor(xp, 4);
            xp += __shfl_xor(xp, 8);
            if (es == 0) xsl[r16] = (float)xp;    // fl32(exact ||x||^2)
        }
        __syncthreads();                          // xs + xsl ready

        // ---- 4q x 4c micro-tile; c rows straight from L1/L2 ----
        const int crow0 = tile * 128 + chalf * 64 + ch * 32 + cg * 4;
        double a[4][4];
        #pragma unroll
        for (int qi = 0; qi < 4; ++qi)
            #pragma unroll
            for (int ci = 0; ci < 4; ++ci) a[qi][ci] = 0.0;

        const float* __restrict__ xq = &xs[(qg * 4) * S258 + ds * 4];
        const float* __restrict__ cq = cb + (size_t)crow0 * 256 + ds * 4;
        #pragma unroll 4
        for (int dd = 0; dd < 16; ++dd) {
            const int off = dd * 16;              // dims dd*16 + ds*4 + j
            float4 xv[4], cv[4];
            #pragma unroll
            for (int qi = 0; qi < 4; ++qi)
                xv[qi] = *(const float4*)&xq[qi * S258 + off];
            #pragma unroll
            for (int ci = 0; ci < 4; ++ci)
                cv[ci] = *(const float4*)&cq[ci * 256 + off];   // global, L1-hot
            #pragma unroll
            for (int qi = 0; qi < 4; ++qi)
                #pragma unroll
                for (int ci = 0; ci < 4; ++ci) {
                    a[qi][ci] = fma((double)xv[qi].x, (double)cv[ci].x, a[qi][ci]);
                    a[qi][ci] = fma((double)xv[qi].y, (double)cv[ci].y, a[qi][ci]);
                    a[qi][ci] = fma((double)xv[qi].z, (double)cv[ci].z, a[qi][ci]);
                    a[qi][ci] = fma((double)xv[qi].w, (double)cv[ci].w, a[qi][ci]);
                }
        }

        // reduce dim quarters (lanes xor 1,2) -> ds==0 holds full fp64 dots
        #pragma unroll
        for (int qi = 0; qi < 4; ++qi)
            #pragma unroll
            for (int ci = 0; ci < 4; ++ci) {
                double v = a[qi][ci];
                v += __shfl_xor(v, 1);
                v += __shfl_xor(v, 2);
                a[qi][ci] = v;
            }
        if (ds == 0) {
            float4 csqv = *(const float4*)&csq[crow0];
            #pragma unroll
            for (int qi = 0; qi < 4; ++qi) {
                const float xsv = xsl[qg * 4 + qi];
                u64 pk = ~0ULL;
                #pragma unroll
                for (int ci = 0; ci < 4; ++ci) {
                    float g = (float)a[qi][ci];            // fl32(exact dot)
                    float G = g + g;
                    float csv = (ci == 0) ? csqv.x : (ci == 1) ? csqv.y
                              : (ci == 2) ? csqv.z : csqv.w;
                    float d = (xsv - G) + csv;             // fp32 rounding replay
                    uint gidx = (uint)(crow0 + ci);
                    pk = u64min(pk, ((u64)__float_as_uint(d) << 32) | gidx);
                }
                atomicMin(&pkq[qg * 4 + qi], pk);
            }
        }
        __syncthreads();                           // pkq final
        if (t < nq) atomicMin(&best64[qids[t]], pkq[t]);   // (d, idx): numpy tiebreak
    }
}

// ---- gather: 512 blocks, 4 threads/query (verified in R16 phase 3) ----
__global__ __launch_bounds__(256)
void vq_gather(const float* __restrict__ cb, const int* __restrict__ idxout,
               const u64* __restrict__ best64, float* __restrict__ out) {
    int t  = threadIdx.x;
    int n  = blockIdx.x * 64 + (t >> 2);
    int eg = t & 3;
    u64 pk = best64[n];
    int bi = (pk != ~0ULL) ? (int)(pk & 0xffffffffu) : idxout[n];
    int b = n >> 10, hw = n & 1023;
    const float4* __restrict__ row = (const float4*)(cb + (size_t)bi * 256);
    float* __restrict__ outB = out + (size_t)b * 256 * HW + hw;
    #pragma unroll 4
    for (int j = 0; j < 16; ++j) {
        int e4 = eg * 16 + j;
        float4 c = row[e4];
        outB[(size_t)(e4 * 4 + 0) * HW] = c.x;
        outB[(size_t)(e4 * 4 + 1) * HW] = c.y;
        outB[(size_t)(e4 * 4 + 2) * HW] = c.z;
        outB[(size_t)(e4 * 4 + 3) * HW] = c.w;
    }
}

extern "C" void kernel_launch(void* const* d_in, const int* in_sizes, int n_in,
                              void* d_out, int out_size, void* d_ws, size_t ws_size,
                              hipStream_t stream) {
    const float* emb = (const float*)d_in[0];   // [32, 256, 32, 32] fp32
    const float* cb  = (const float*)d_in[1];   // [2048, 256] fp32
    float* out = (float*)d_out;

    char* ws = (char*)d_ws;
    ushort* xb     = (ushort*)ws;                        // 16 MB
    ushort* cb1    = (ushort*)(ws + 16777216);           // 1 MB
    float*  csq    = (float*) (ws + 17825792);           // 8 KB
    float*  pm1    = (float*) (ws + 17833984);           // 2 MB  [16][NQ]
    float*  pm2    = (float*) (ws + 19931136);           // 2 MB  [16][NQ]
    uint*   pidxg  = (uint*)  (ws + 22028288);           // 2 MB  [16][NQ]
    int*    idxout = (int*)   (ws + 24125440);           // 128 KB
    int*    bucket = (int*)   (ws + 24256512);           // 2 MB (16 x 32768)
    int*    cnt    = (int*)   (ws + 26353664);           // 256 B
    u64*    best64 = (u64*)   (ws + 26353920);           // 256 KB
    float*  xt     = (float*) (ws + 26616064);           // 32 MB (optional)
    int use_xt = (ws_size >= (size_t)26616064 + 33554432) ? 1 : 0;

    prep_all <<<2560, 256, 0, stream>>>(emb, cb, xb, cb1, csq, xt, use_xt, cnt);
    vq_gemm2 <<<4096, 256, 0, stream>>>(xb, cb1, csq, pm1, pm2, pidxg);
    vq_merge <<<128,  256, 0, stream>>>(pm1, pm2, pidxg, idxout, bucket, cnt, best64);
    vq_exact5<<<1024, 256, 0, stream>>>(emb, xt, use_xt, cb, csq, bucket, cnt, best64);
    vq_gather<<<512,  256, 0, stream>>>(cb, idxout, best64, out);
}

// Round 19
// 153.446 us; speedup vs baseline: 2.0788x; 1.0007x over previous
//
#include <hip/hip_runtime.h>

typedef unsigned int uint;
typedef unsigned short ushort;
typedef unsigned long long u64;
typedef __attribute__((ext_vector_type(8))) short short8v;   // 8 bf16 in 4 VGPRs
typedef __attribute__((ext_vector_type(4))) float float4v;

#define NQ    32768
#define KALL  2048
#define E_DIM 256
#define HW    1024
#define TAU   2.5e-4f
#define S258  258     // fp32 LDS row stride for exact stage (2-way max on all ops)

// async global->LDS, 16B per lane; LDS dest = wave-uniform base + lane*16
#define GLOAD16(gsrc, ldst) \
    __builtin_amdgcn_global_load_lds( \
        (const __attribute__((address_space(1))) void*)(gsrc), \
        (__attribute__((address_space(3))) void*)(ldst), 16, 0, 0)

static __device__ __forceinline__ ushort f2bf(float f) {
    uint u = __float_as_uint(f);
    uint r = (u + 0x7fffu + ((u >> 16) & 1u)) >> 16;   // RNE, no NaN inputs
    return (ushort)r;
}

static __device__ __forceinline__ u64 u64min(u64 a, u64 b) { return a < b ? a : b; }

// ---- fused prep: blocks [0,512): codebook -> bf16 + csq (+ cnt zero);
// ----             blocks [512,2560): emb -> xb bf16 (+ xt fp32) ----
__global__ __launch_bounds__(256)
void prep_all(const float* __restrict__ emb, const float* __restrict__ cb,
              ushort* __restrict__ xb, ushort* __restrict__ cb1,
              float* __restrict__ csq, float* __restrict__ xt, int use_xt,
              int* __restrict__ cnt) {
    __shared__ float ldsf[64 * 65];
    const int t = threadIdx.x;

    if (blockIdx.x < 512) {               // ---- prep_cb ----
        if (blockIdx.x == 0 && t < 16) cnt[t] = 0;   // replaces memset launch
        int row  = blockIdx.x * 4 + (t >> 6);
        int lane = t & 63;
        float4 v = ((const float4*)cb)[row * 64 + lane];
        double s = (double)v.x * v.x + (double)v.y * v.y +
                   (double)v.z * v.z + (double)v.w * v.w;
        for (int m = 1; m < 64; m <<= 1) s += __shfl_xor(s, m);
        if (lane == 0) csq[row] = (float)s;    // fl32(exact ||c||^2)
        uint u0 = (uint)f2bf(v.x) | ((uint)f2bf(v.y) << 16);
        uint u1 = (uint)f2bf(v.z) | ((uint)f2bf(v.w) << 16);
        ((uint2*)cb1)[row * 64 + lane] = make_uint2(u0, u1);
        return;
    }

    // ---- prep_x ----
    int blk = blockIdx.x - 512;
    int img = blk >> 6;
    int tile = blk & 63;
    int e0  = (tile >> 4) * 64;
    int hw0 = (tile & 15) * 64;
    int rr4 = t >> 4;         // 0..15
    int c4  = t & 15;         // 0..15
    #pragma unroll
    for (int p = 0; p < 4; ++p) {          // float4 loads: 4 instrs vs 16 scalar
        int r = p * 16 + rr4;
        float4 v = *(const float4*)&emb[((img * 256 + e0 + r) << 10) + hw0 + c4 * 4];
        ldsf[(c4 * 4 + 0) * 65 + r] = v.x; // transpose into LDS (<=2-way: free)
        ldsf[(c4 * 4 + 1) * 65 + r] = v.y;
        ldsf[(c4 * 4 + 2) * 65 + r] = v.z;
        ldsf[(c4 * 4 + 3) * 65 + r] = v.w;
    }
    __syncthreads();
    int hr = t >> 5;          // 0..7
    int ep = t & 31;
    #pragma unroll 4
    for (int i = 0; i < 8; ++i) {
        int hwr = i * 8 + hr;
        float v0 = ldsf[hwr * 65 + ep * 2];
        float v1 = ldsf[hwr * 65 + ep * 2 + 1];
        uint u = (uint)f2bf(v0) | ((uint)f2bf(v1) << 16);
        size_t n = (size_t)(img * 1024 + hw0 + hwr);
        ((uint*)xb)[(n << 7) + (e0 >> 1) + ep] = u;
        if (use_xt)
            *(float2*)&xt[(n << 8) + e0 + ep * 2] = make_float2(v0, v1);
    }
}

// -- stage 1: bf16 MFMA GEMM, 2-phase dbuf + counted vmcnt, reg-top2 epilogue --
// Swapped-operand MFMA: D-rows = codes, D-cols = queries. (proven round-10/13/17 form)
__global__ __launch_bounds__(256, 2)
void vq_gemm2(const ushort* __restrict__ xb, const ushort* __restrict__ cb1,
              const float* __restrict__ csq,
              float* __restrict__ pm1, float* __restrict__ pm2,
              uint* __restrict__ pidxg) {
    __shared__ char stg[2][32768];       // [buf][ A 16KB | B 16KB ]
    __shared__ float e1[128][9];
    __shared__ float e2[128][9];
    __shared__ uint  ei[128][9];

    const int t = threadIdx.x;
    // XCD-chunked bijective swizzle (4096 blocks, 8 XCDs, 512 per XCD)
    const int bi = ((blockIdx.x & 7) << 9) | (blockIdx.x >> 3);
    const int mt = bi >> 4;              // 256 M-tiles
    const int nt = bi & 15;              // 16 N-tiles
    const int qbase = mt * 128;
    const int cbase = nt * 128;

    const int wid = t >> 6, lane = t & 63;
    const int wr = wid >> 1, wc = wid & 1;
    const int lr = lane & 15, lk = lane >> 4;

    float4v acc[4][4];                   // [fj: code blk][fi: query blk]
    #pragma unroll
    for (int i = 0; i < 4; ++i)
        #pragma unroll
        for (int j = 0; j < 4; ++j)
            acc[i][j] = (float4v){0.f, 0.f, 0.f, 0.f};

    const int srow = lane >> 3;          // 0..7 within 8-row chunk
    const int sslot = lane & 7;          // 16B slot within row

    // prologue: stage K-step 0 into buf 0
    #pragma unroll
    for (int i = 0; i < 4; ++i) {
        int ch  = wid * 4 + i;
        int row = ch * 8 + srow;
        int sl  = sslot ^ (row & 7);
        GLOAD16(xb  + (size_t)(qbase + row) * 256 + sl * 8, &stg[0][0]     + ch * 1024);
        GLOAD16(cb1 + (size_t)(cbase + row) * 256 + sl * 8, &stg[0][16384] + ch * 1024);
    }

    #pragma unroll
    for (int kt = 0; kt < 4; ++kt) {
        const int cur = kt & 1;
        if (kt < 3) {                    // stage next K-step into other buf
            const int kofs = (kt + 1) * 64;
            #pragma unroll
            for (int i = 0; i < 4; ++i) {
                int ch  = wid * 4 + i;
                int row = ch * 8 + srow;
                int sl  = sslot ^ (row & 7);
                GLOAD16(xb  + (size_t)(qbase + row) * 256 + kofs + sl * 8,
                        &stg[cur ^ 1][0] + ch * 1024);
                GLOAD16(cb1 + (size_t)(cbase + row) * 256 + kofs + sl * 8,
                        &stg[cur ^ 1][16384] + ch * 1024);
            }
            asm volatile("s_waitcnt vmcnt(8)" ::: "memory");   // current buf landed
        } else {
            asm volatile("s_waitcnt vmcnt(0)" ::: "memory");
        }
        __builtin_amdgcn_sched_barrier(0);
        __builtin_amdgcn_s_barrier();    // all waves' loads landed
        __builtin_amdgcn_sched_barrier(0);

        const char* Asm = &stg[cur][0];
        const char* Bsm = &stg[cur][16384];
        #pragma unroll
        for (int ks = 0; ks < 2; ++ks) {
            short8v af[4], bfv[4];
            #pragma unroll
            for (int f = 0; f < 4; ++f) {
                int ra = wr * 64 + f * 16 + lr;
                int sa = ((ks << 2) | lk) ^ (ra & 7);
                af[f] = *(const short8v*)(Asm + ra * 128 + sa * 16);
                int rb = wc * 64 + f * 16 + lr;
                int sb = ((ks << 2) | lk) ^ (rb & 7);
                bfv[f] = *(const short8v*)(Bsm + rb * 128 + sb * 16);
            }
            #pragma unroll
            for (int fj = 0; fj < 4; ++fj)
                #pragma unroll
                for (int fi = 0; fi < 4; ++fi)
                    acc[fj][fi] = __builtin_amdgcn_mfma_f32_16x16x32_bf16(
                        bfv[fj], af[fi], acc[fj][fi], 0, 0, 0);
        }
        __builtin_amdgcn_s_barrier();    // reads retired; buffer reusable
    }

    // per-lane csq for its 16 codes (cloc = wc*64 + fj*16 + lk*4 + r); L2-hot
    float csqv[16];
    #pragma unroll
    for (int fj = 0; fj < 4; ++fj)
        #pragma unroll
        for (int r = 0; r < 4; ++r)
            csqv[fj * 4 + r] = csq[cbase + wc * 64 + fj * 16 + lk * 4 + r];

    // phase 1: per-lane top2 over 16 codes for query (fi, lr); write [q][wc*4+lk]
    #pragma unroll
    for (int fi = 0; fi < 4; ++fi) {
        float m1 = 3e38f, m2 = 3e38f; uint i1 = 0;
        #pragma unroll
        for (int fj = 0; fj < 4; ++fj)
            #pragma unroll
            for (int r = 0; r < 4; ++r) {
                float s = fmaf(-2.0f, acc[fj][fi][r], csqv[fj * 4 + r]);
                uint gidx = (uint)(cbase + wc * 64 + fj * 16 + lk * 4 + r);
                if (s < m1) { m2 = m1; m1 = s; i1 = gidx; }
                else        { m2 = fminf(m2, s); }
            }
        int q = wr * 64 + fi * 16 + lr;
        int col = wc * 4 + lk;
        e1[q][col] = m1; e2[q][col] = m2; ei[q][col] = i1;
    }
    __syncthreads();

    // phase 2: q = t>>1; halves merge 4 entries each, then shfl_xor(1)
    {
        int q = t >> 1, h = t & 1;
        float m1 = 3e38f, m2 = 3e38f; uint i1 = 0;
        #pragma unroll
        for (int j = 0; j < 4; ++j) {
            int col = h * 4 + j;
            float a1 = e1[q][col], a2 = e2[q][col];
            uint  ai = ei[q][col];
            if (a1 < m1) { m2 = fminf(m1, a2); m1 = a1; i1 = ai; }
            else         { m2 = fminf(m2, a1); }
        }
        float o1 = __shfl_xor(m1, 1);
        float o2 = __shfl_xor(m2, 1);
        uint  oi = __shfl_xor(i1, 1);
        if (o1 < m1) { m2 = fminf(m1, o2); m1 = o1; i1 = oi; }
        else         { m2 = fminf(m2, o1); }
        if (h == 0) {
            size_t og = (size_t)nt * NQ + qbase + q;   // [nt][NQ]: coalesced
            pm1[og] = m1;
            pm2[og] = m2;
            pidxg[og] = i1;
        }
    }
}

// ---- merge tiles, flag near-ties into per-tile buckets; init best64 ----
__global__ __launch_bounds__(256)
void vq_merge(const float* __restrict__ pm1, const float* __restrict__ pm2,
              const uint* __restrict__ pidxg, int* __restrict__ idxout,
              int* __restrict__ bucket, int* __restrict__ cnt,
              u64* __restrict__ best64) {
    int q = blockIdx.x * 256 + threadIdx.x;
    best64[q] = ~0ULL;                    // replaces memset launch (runs pre-exact5)
    float g1 = 3e38f, g2 = 3e38f; uint gi = 0;
    float m1v[16];
    #pragma unroll
    for (int tl = 0; tl < 16; ++tl) {
        float a1 = pm1[(size_t)tl * NQ + q];
        float a2 = pm2[(size_t)tl * NQ + q];
        uint  ai = pidxg[(size_t)tl * NQ + q];
        m1v[tl] = a1;
        if (a1 < g1) { g2 = fminf(g1, a2); g1 = a1; gi = ai; }
        else         { g2 = fminf(g2, a1); }
    }
    idxout[q] = (int)gi;
    if (g2 - g1 < TAU) {
        float lim = g1 + TAU;
        #pragma unroll
        for (int tl = 0; tl < 16; ++tl) {
            if (m1v[tl] < lim) {           // candidate tile: could hold the true winner
                int p = atomicAdd(&cnt[tl], 1);
                bucket[tl * NQ + p] = q;
            }
        }
    }
}

// ------- stage 2: exact fp64 micro-GEMM; x in LDS, codebook direct from L2 -------
__global__ __launch_bounds__(256)
void vq_exact5(const float* __restrict__ emb, const float* __restrict__ xt,
               int use_xt, const float* __restrict__ cb,
               const float* __restrict__ csq, const int* __restrict__ bucket,
               const int* __restrict__ cnt, u64* __restrict__ best64) {
    __shared__ float xs[16 * S258];      // 16.5 KB: 16 query rows, fp32
    __shared__ u64   pkq[16];
    __shared__ float xsl[16];
    __shared__ int   qids[16];

    const int tile  = blockIdx.x >> 6;        // 0..15
    const int qslot = (blockIdx.x >> 1) & 31; // 0..31
    const int chalf = blockIdx.x & 1;         // 0..1
    const int t  = threadIdx.x;
    const int cn = cnt[tile];

    const int r16 = t >> 4, es = t & 15;  // staging: 16 rows x 16 lanes
    const int ds = t & 3;                 // dim quarter
    const int p  = t >> 2;                // 0..63
    const int cg = p & 7, qg = (p >> 3) & 3, ch = p >> 5;

    for (int base = qslot * 16; base < cn; base += 32 * 16) {
        const int nq = min(16, cn - base);
        __syncthreads();                          // prior iteration fully done
        if (t < 16) {
            pkq[t]  = ~0ULL;
            qids[t] = (t < nq) ? bucket[tile * NQ + base + t] : 0;
        }
        __syncthreads();

        // ---- stage 16 query rows (fp32) + exact ||x||^2 ----
        {
            double xp = 0.0;
            float* xrow = &xs[r16 * S258];
            if (r16 < nq) {
                const int q = qids[r16];
                if (use_xt) {                     // coalesced: 16 lanes x 4 float4
                    const float4* __restrict__ src = (const float4*)(xt + ((size_t)q << 8));
                    #pragma unroll
                    for (int j = 0; j < 4; ++j) { // dims j*64 + es*4 .. +3
                        float4 v = src[j * 16 + es];
                        *(float4*)&xrow[j * 64 + es * 4] = v;
                        xp = fma((double)v.x, (double)v.x, xp);
                        xp = fma((double)v.y, (double)v.y, xp);
                        xp = fma((double)v.z, (double)v.z, xp);
                        xp = fma((double)v.w, (double)v.w, xp);
                    }
                } else {                          // fallback: scattered 4B loads
                    const int b = q >> 10, hw = q & 1023;
                    const float* __restrict__ ep = emb + ((size_t)b << 18) + hw;
                    #pragma unroll
                    for (int j = 0; j < 4; ++j) {
                        float vv[4];
                        #pragma unroll
                        for (int jj = 0; jj < 4; ++jj) {
                            int e = j * 64 + es * 4 + jj;
                            vv[jj] = ep[(size_t)e << 10];
                            xp = fma((double)vv[jj], (double)vv[jj], xp);
                        }
                        *(float4*)&xrow[j * 64 + es * 4] =
                            make_float4(vv[0], vv[1], vv[2], vv[3]);
                    }
                }
            } else {
                #pragma unroll
                for (int j = 0; j < 4; ++j)
                    *(float4*)&xrow[j * 64 + es * 4] = make_float4(0.f, 0.f, 0.f, 0.f);
            }
            xp += __shfl_xor(xp, 1);
            xp += __shfl_xor(xp, 2);
            xp += __shfl_xor(xp, 4);
            xp += __shfl_xor(xp, 8);
            if (es == 0) xsl[r16] = (float)xp;    // fl32(exact ||x||^2)
        }
        __syncthreads();                          // xs + xsl ready

        // ---- 4q x 4c micro-tile; c rows straight from L1/L2 ----
        const int crow0 = tile * 128 + chalf * 64 + ch * 32 + cg * 4;
        double a[4][4];
        #pragma unroll
        for (int qi = 0; qi < 4; ++qi)
            #pragma unroll
            for (int ci = 0; ci < 4; ++ci) a[qi][ci] = 0.0;

        const float* __restrict__ xq = &xs[(qg * 4) * S258 + ds * 4];
        const float* __restrict__ cq = cb + (size_t)crow0 * 256 + ds * 4;
        #pragma unroll 4
        for (int dd = 0; dd < 16; ++dd) {
            const int off = dd * 16;              // dims dd*16 + ds*4 + j
            float4 xv[4], cv[4];
            #pragma unroll
            for (int qi = 0; qi < 4; ++qi)
                xv[qi] = *(const float4*)&xq[qi * S258 + off];
            #pragma unroll
            for (int ci = 0; ci < 4; ++ci)
                cv[ci] = *(const float4*)&cq[ci * 256 + off];   // global, L1-hot
            #pragma unroll
            for (int qi = 0; qi < 4; ++qi)
                #pragma unroll
                for (int ci = 0; ci < 4; ++ci) {
                    a[qi][ci] = fma((double)xv[qi].x, (double)cv[ci].x, a[qi][ci]);
                    a[qi][ci] = fma((double)xv[qi].y, (double)cv[ci].y, a[qi][ci]);
                    a[qi][ci] = fma((double)xv[qi].z, (double)cv[ci].z, a[qi][ci]);
                    a[qi][ci] = fma((double)xv[qi].w, (double)cv[ci].w, a[qi][ci]);
                }
        }

        // reduce dim quarters (lanes xor 1,2) -> ds==0 holds full fp64 dots
        #pragma unroll
        for (int qi = 0; qi < 4; ++qi)
            #pragma unroll
            for (int ci = 0; ci < 4; ++ci) {
                double v = a[qi][ci];
                v += __shfl_xor(v, 1);
                v += __shfl_xor(v, 2);
                a[qi][ci] = v;
            }
        if (ds == 0) {
            float4 csqv = *(const float4*)&csq[crow0];
            #pragma unroll
            for (int qi = 0; qi < 4; ++qi) {
                const float xsv = xsl[qg * 4 + qi];
                u64 pk = ~0ULL;
                #pragma unroll
                for (int ci = 0; ci < 4; ++ci) {
                    float g = (float)a[qi][ci];            // fl32(exact dot)
                    float G = g + g;
                    float csv = (ci == 0) ? csqv.x : (ci == 1) ? csqv.y
                              : (ci == 2) ? csqv.z : csqv.w;
                    float d = (xsv - G) + csv;             // fp32 rounding replay
                    uint gidx = (uint)(crow0 + ci);
                    pk = u64min(pk, ((u64)__float_as_uint(d) << 32) | gidx);
                }
                atomicMin(&pkq[qg * 4 + qi], pk);
            }
        }
        __syncthreads();                           // pkq final
        if (t < nq) atomicMin(&best64[qids[t]], pkq[t]);   // (d, idx): numpy tiebreak
    }
}

// ---- gather: 512 blocks, 4 threads/query ----
__global__ __launch_bounds__(256)
void vq_gather(const float* __restrict__ cb, const int* __restrict__ idxout,
               const u64* __restrict__ best64, float* __restrict__ out) {
    int t  = threadIdx.x;
    int n  = blockIdx.x * 64 + (t >> 2);
    int eg = t & 3;
    u64 pk = best64[n];
    int bi = (pk != ~0ULL) ? (int)(pk & 0xffffffffu) : idxout[n];
    int b = n >> 10, hw = n & 1023;
    const float4* __restrict__ row = (const float4*)(cb + (size_t)bi * 256);
    float* __restrict__ outB = out + (size_t)b * 256 * HW + hw;
    #pragma unroll 4
    for (int j = 0; j < 16; ++j) {
        int e4 = eg * 16 + j;
        float4 c = row[e4];
        outB[(size_t)(e4 * 4 + 0) * HW] = c.x;
        outB[(size_t)(e4 * 4 + 1) * HW] = c.y;
        outB[(size_t)(e4 * 4 + 2) * HW] = c.z;
        outB[(size_t)(e4 * 4 + 3) * HW] = c.w;
    }
}

extern "C" void kernel_launch(void* const* d_in, const int* in_sizes, int n_in,
                              void* d_out, int out_size, void* d_ws, size_t ws_size,
                              hipStream_t stream) {
    const float* emb = (const float*)d_in[0];   // [32, 256, 32, 32] fp32
    const float* cb  = (const float*)d_in[1];   // [2048, 256] fp32
    float* out = (float*)d_out;

    char* ws = (char*)d_ws;
    ushort* xb     = (ushort*)ws;                        // 16 MB
    ushort* cb1    = (ushort*)(ws + 16777216);           // 1 MB
    float*  csq    = (float*) (ws + 17825792);           // 8 KB
    float*  pm1    = (float*) (ws + 17833984);           // 2 MB  [16][NQ]
    float*  pm2    = (float*) (ws + 19931136);           // 2 MB  [16][NQ]
    uint*   pidxg  = (uint*)  (ws + 22028288);           // 2 MB  [16][NQ]
    int*    idxout = (int*)   (ws + 24125440);           // 128 KB
    int*    bucket = (int*)   (ws + 24256512);           // 2 MB (16 x 32768)
    int*    cnt    = (int*)   (ws + 26353664);           // 256 B
    u64*    best64 = (u64*)   (ws + 26353920);           // 256 KB
    float*  xt     = (float*) (ws + 26616064);           // 32 MB (optional)
    int use_xt = (ws_size >= (size_t)26616064 + 33554432) ? 1 : 0;

    prep_all <<<2560, 256, 0, stream>>>(emb, cb, xb, cb1, csq, xt, use_xt, cnt);
    vq_gemm2 <<<4096, 256, 0, stream>>>(xb, cb1, csq, pm1, pm2, pidxg);
    vq_merge <<<128,  256, 0, stream>>>(pm1, pm2, pidxg, idxout, bucket, cnt, best64);
    vq_exact5<<<1024, 256, 0, stream>>>(emb, xt, use_xt, cb, csq, bucket, cnt, best64);
    vq_gather<<<512,  256, 0, stream>>>(cb, idxout, best64, out);
}